// Round 10
// baseline (262.272 us; speedup 1.0000x reference)
//
#include <hip/hip_runtime.h>

#define NI 2048
#define NB 64
#define NC 32
#define DC 16
#define DI 8

static constexpr float SQ_EPS = 1e-7f;

// SSA vector type: never an alloca, never scratch (R8 lesson).
typedef float f8 __attribute__((ext_vector_type(8)));

// Routing pass, W double-buffered through LDS, b-quad per wave.
// R9 post-mortem: at 2 waves/EU the kernel is latency-bound (DS pipe 48%,
// VALU 36%, neither saturated). This version: grid (NIB=256 i-blocks of 8
// capsules, 4 b-quarters) = 1024 blocks -> 4 blocks/CU of 256-thread
// blocks at waves_per_eu(3,3) = 12 waves/CU, and a 2-buffer W pipeline
// (load capsule k+1 into regs BEFORE computing capsule k; ds_write after)
// so VMEM latency hides under compute instead of under a barrier.
// Lane = (c = lane&31, dg = lane>>5); wave owns b-quad by*16 + wave*4.
// MODE 0: uniform coupling 1/32. MODE 1: logits = dot(u, veff),
// veff transposed [b][dg][c][8].
template <int MODE>
__global__
__attribute__((amdgpu_flat_work_group_size(256, 256), amdgpu_waves_per_eu(3, 3)))
void route_pass(
    const float* __restrict__ x, const float* __restrict__ W,
    const float* __restrict__ veff, float* __restrict__ partial)
{
    // Per-capsule W tile: slot m = 2*(k&15)+(k>>4), layout [m 32][c 33]
    // float4 (33-stride -> read runs are c-contiguous, 2-way max aliasing).
    __shared__ float4 wtile[2][1056];   // 33 KB
    __shared__ float4 xbuf[512];        // [brel 16][ii][half], 8 KB

    const int ncap = NI / gridDim.x;                // 8 (16 in ws fallback)
    const int lgn2 = __builtin_ctz(ncap) + 1;       // log2(ncap*2)
    const int tid  = threadIdx.x;
    const int wave = tid >> 6;
    const int lane = tid & 63;
    const int c    = lane & 31;
    const int dg   = lane >> 5;
    const int brel0 = wave * 4;
    const int b0g  = blockIdx.y * 16;
    const int b0   = b0g + brel0;
    const int i0   = blockIdx.x * ncap;

    f8 s0 = {}, s1 = {}, s2 = {}, s3 = {};
    f8 va = {}, vb = {}, vc = {}, vd = {};
    if (MODE == 1) {
        va = *reinterpret_cast<const f8*>(veff + (((size_t)(b0+0)*2 + dg)*32 + c)*8);
        vb = *reinterpret_cast<const f8*>(veff + (((size_t)(b0+1)*2 + dg)*32 + c)*8);
        vc = *reinterpret_cast<const f8*>(veff + (((size_t)(b0+2)*2 + dg)*32 + c)*8);
        vd = *reinterpret_cast<const f8*>(veff + (((size_t)(b0+3)*2 + dg)*32 + c)*8);
    }

    const float4* Wf4 = reinterpret_cast<const float4*>(W);
    const float4* Xf4 = reinterpret_cast<const float4*>(x);
    const int kk  = tid & 31;          // f4 index within a (c,i) W row
    const int cc0 = tid >> 5;          // 0..7
    const int sb  = ((kk & 15) * 2 + (kk >> 4)) * 33;   // LDS slot base

    // ---- stage x tile: 16 b x ncap i x 8 f  (one-time)
    for (int idx = tid; idx < (16 << lgn2); idx += 256) {
        const int brel = idx >> lgn2;
        const int rem  = idx & ((1 << lgn2) - 1);       // ii*2 + half
        xbuf[brel * 32 + rem] =
            Xf4[((size_t)(b0g + brel) * NI + i0 + (rem >> 1)) * 2 + (rem & 1)];
    }
    // ---- preload + write W capsule 0 into buffer 0
    {
        float4 t0 = Wf4[((size_t)(cc0     ) * NI + i0) * 32 + kk];
        float4 t1 = Wf4[((size_t)(cc0 +  8) * NI + i0) * 32 + kk];
        float4 t2 = Wf4[((size_t)(cc0 + 16) * NI + i0) * 32 + kk];
        float4 t3 = Wf4[((size_t)(cc0 + 24) * NI + i0) * 32 + kk];
        wtile[0][sb + cc0     ] = t0;
        wtile[0][sb + cc0 +  8] = t1;
        wtile[0][sb + cc0 + 16] = t2;
        wtile[0][sb + cc0 + 24] = t3;
    }
    __syncthreads();

    for (int cap = 0; cap < ncap; ++cap) {
        // issue next capsule's global loads early (hide under compute)
        float4 t0, t1, t2, t3;
        const bool more = (cap + 1 < ncap);
        if (more) {
            const int ip = i0 + cap + 1;
            t0 = Wf4[((size_t)(cc0     ) * NI + ip) * 32 + kk];
            t1 = Wf4[((size_t)(cc0 +  8) * NI + ip) * 32 + kk];
            t2 = Wf4[((size_t)(cc0 + 16) * NI + ip) * 32 + kk];
            t3 = Wf4[((size_t)(cc0 + 24) * NI + ip) * 32 + kk];
        }

        // ---- compute on buffer cap&1
        {
            const float4* wt = wtile[cap & 1];
            const float4 xa0 = xbuf[(brel0+0)*32 + cap*2], xa1 = xbuf[(brel0+0)*32 + cap*2 + 1];
            const float4 xb0 = xbuf[(brel0+1)*32 + cap*2], xb1 = xbuf[(brel0+1)*32 + cap*2 + 1];
            const float4 xc0 = xbuf[(brel0+2)*32 + cap*2], xc1 = xbuf[(brel0+2)*32 + cap*2 + 1];
            const float4 xd0 = xbuf[(brel0+3)*32 + cap*2], xd1 = xbuf[(brel0+3)*32 + cap*2 + 1];

            f8 u0 = {}, u1 = {}, u2 = {}, u3 = {};
#pragma unroll
            for (int dd = 0; dd < 8; ++dd) {
                const float4 wl = wt[(4*dd     + dg)*33 + c];
                const float4 wh = wt[(4*dd + 2 + dg)*33 + c];
                u0[dd] = wl.x*xa0.x + wl.y*xa0.y + wl.z*xa0.z + wl.w*xa0.w
                       + wh.x*xa1.x + wh.y*xa1.y + wh.z*xa1.z + wh.w*xa1.w;
                u1[dd] = wl.x*xb0.x + wl.y*xb0.y + wl.z*xb0.z + wl.w*xb0.w
                       + wh.x*xb1.x + wh.y*xb1.y + wh.z*xb1.z + wh.w*xb1.w;
                u2[dd] = wl.x*xc0.x + wl.y*xc0.y + wl.z*xc0.z + wl.w*xc0.w
                       + wh.x*xc1.x + wh.y*xc1.y + wh.z*xc1.z + wh.w*xc1.w;
                u3[dd] = wl.x*xd0.x + wl.y*xd0.y + wl.z*xd0.z + wl.w*xd0.w
                       + wh.x*xd1.x + wh.y*xd1.y + wh.z*xd1.z + wh.w*xd1.w;
            }

            if (MODE == 0) {
                const float cu = 1.0f / 32.0f;
                s0 += u0 * cu; s1 += u1 * cu; s2 += u2 * cu; s3 += u3 * cu;
            } else {
                // Pair-softmax: lower 32-half reduces the even b, upper the
                // odd b; one xor-32 merge in, one xor-32 coef-swap out.
#pragma unroll
                for (int pr = 0; pr < 2; ++pr) {
                    const f8& ue = pr ? u2 : u0;
                    const f8& uo = pr ? u3 : u1;
                    const f8& ve = pr ? vc : va;
                    const f8& vo = pr ? vd : vb;
                    float pe = 0.0f, po = 0.0f;
#pragma unroll
                    for (int k = 0; k < 8; ++k) {
                        pe += ue[k] * ve[k];
                        po += uo[k] * vo[k];
                    }
                    const float send = (dg == 0) ? po : pe;
                    const float recv = __shfl_xor(send, 32);
                    float a = ((dg == 0) ? pe : po) + recv;
                    float m = a;
#pragma unroll
                    for (int off = 16; off >= 1; off >>= 1)
                        m = fmaxf(m, __shfl_xor(m, off));
                    const float e = __expf(a - m);
                    float t = e;
#pragma unroll
                    for (int off = 16; off >= 1; off >>= 1)
                        t += __shfl_xor(t, off);
                    const float mine  = e / t;
                    const float other = __shfl_xor(mine, 32);
                    const float ce = (dg == 0) ? mine : other;
                    const float co = (dg == 0) ? other : mine;
                    if (pr == 0) { s0 += u0 * ce; s1 += u1 * co; }
                    else         { s2 += u2 * ce; s3 += u3 * co; }
                }
            }
        }

        if (more) {
            __syncthreads();                 // all readers of next buf done
            float4* wn = wtile[(cap + 1) & 1];
            wn[sb + cc0     ] = t0;
            wn[sb + cc0 +  8] = t1;
            wn[sb + cc0 + 16] = t2;
            wn[sb + cc0 + 24] = t3;
            __syncthreads();                 // writes visible before compute
        }
    }

    // ---- flush the wave's four s-partials (plain coalesced 32 B stores)
    // partial floats: [pblk][brel 16][dg 2][c 32][8]
    {
        const int pblk = blockIdx.y * gridDim.x + blockIdx.x;
        float* gp = partial +
            (((size_t)pblk * 16 + brel0) * 128 + dg * 64 + c * 2) * 4;
        *reinterpret_cast<f8*>(gp)        = s0;
        *reinterpret_cast<f8*>(gp +  512) = s1;
        *reinterpret_cast<f8*>(gp + 1024) = s2;
        *reinterpret_cast<f8*>(gp + 1536) = s3;
    }
}

// Fused partial reduction + squash. 64 blocks (one per b) x 512 threads:
// part = tid>>7 sums a quarter of the nib slabs; LDS tree combines; the
// first 128 threads squash+write.
// phase 1: veff  = NI * squash(s)   (transposed [b][dg][c][8])
// phase 2: veff += NI * squash(s)
// phase 3: out   = squash(s)        (canonical [b][c][d])
__global__ __launch_bounds__(512) void reduce_squash(
    const float* __restrict__ partial, float* __restrict__ veff,
    float* __restrict__ out, int phase, int nib)
{
    __shared__ float4 red[512];
    const int b     = blockIdx.x;
    const int tid   = threadIdx.x;
    const int part  = tid >> 7;
    const int inner = tid & 127;
    const int c     = inner >> 2;
    const int dq    = inner & 3;
    const int chunk = nib >> 2;

    const float* base = partial
        + ((size_t)(b >> 4) * nib + part * chunk) * 8192
        + (b & 15) * 512 + (dq >> 1) * 256 + c * 8 + (dq & 1) * 4;
    float4 acc = make_float4(0.f, 0.f, 0.f, 0.f);
#pragma unroll 8
    for (int ib = 0; ib < chunk; ++ib) {
        const float4 p = *reinterpret_cast<const float4*>(base + (size_t)ib * 8192);
        acc.x += p.x; acc.y += p.y; acc.z += p.z; acc.w += p.w;
    }
    red[tid] = acc;
    __syncthreads();
    if (part == 0) {
        const float4 r1 = red[inner + 128], r2 = red[inner + 256], r3 = red[inner + 384];
        acc.x += r1.x + r2.x + r3.x;
        acc.y += r1.y + r2.y + r3.y;
        acc.z += r1.z + r2.z + r3.z;
        acc.w += r1.w + r2.w + r3.w;

        float sq = acc.x*acc.x + acc.y*acc.y + acc.z*acc.z + acc.w*acc.w;
        sq += __shfl_xor(sq, 1);
        sq += __shfl_xor(sq, 2);
        const float scale = sq / ((1.0f + sq) * sqrtf(sq + SQ_EPS));

        if (phase == 3) {
            float4* op = reinterpret_cast<float4*>(
                out + ((size_t)b * NC + c) * DC + dq * 4);
            *op = make_float4(scale*acc.x, scale*acc.y, scale*acc.z, scale*acc.w);
        } else {
            const float ns = scale * (float)NI;
            float4* vp = reinterpret_cast<float4*>(
                veff + (((size_t)b * 2 + (dq >> 1)) * 32 + c) * 8 + (dq & 1) * 4);
            if (phase == 1) {
                *vp = make_float4(ns*acc.x, ns*acc.y, ns*acc.z, ns*acc.w);
            } else {
                float4 old = *vp;
                *vp = make_float4(old.x + ns*acc.x, old.y + ns*acc.y,
                                  old.z + ns*acc.z, old.w + ns*acc.w);
            }
        }
    }
}

extern "C" void kernel_launch(void* const* d_in, const int* in_sizes, int n_in,
                              void* d_out, int out_size, void* d_ws, size_t ws_size,
                              hipStream_t stream) {
    (void)in_sizes; (void)n_in; (void)out_size;
    const float* x = (const float*)d_in[0];
    const float* W = (const float*)d_in[1];

    float* partial = (float*)d_ws;
    float* veff    = (float*)d_out;     // scratch; phase-3 squash overwrites

    // 256 i-blocks needs 4*256 slabs * 32 KB = 33.6 MB of ws; fall back to
    // the 128-block config (16.8 MB) if the workspace is smaller.
    const int nib = (ws_size >= (size_t)4 * 256 * 8192 * 4) ? 256 : 128;
    const dim3 grid(nib, 4);

    // ---- iteration 1: uniform coupling
    route_pass<0><<<grid, 256, 0, stream>>>(x, W, nullptr, partial);
    reduce_squash<<<64, 512, 0, stream>>>(partial, veff, nullptr, 1, nib);

    // ---- iteration 2: logits = NI * <u, v1>
    route_pass<1><<<grid, 256, 0, stream>>>(x, W, veff, partial);
    reduce_squash<<<64, 512, 0, stream>>>(partial, veff, nullptr, 2, nib);

    // ---- iteration 3: logits = NI * (<u, v1> + <u, v2>)
    route_pass<1><<<grid, 256, 0, stream>>>(x, W, veff, partial);
    reduce_squash<<<64, 512, 0, stream>>>(partial, nullptr, (float*)d_out, 3, nib);
}

// Round 11
// 207.135 us; speedup vs baseline: 1.2662x; 1.2662x over previous
//
#include <hip/hip_runtime.h>

#define NI 2048
#define NB 64
#define NC 32
#define DC 16
#define DI 8

static constexpr float SQ_EPS = 1e-7f;

// SSA vector type: never an alloca, never scratch (R8 lesson).
typedef float f8 __attribute__((ext_vector_type(8)));

// Routing pass, W streamed from LDS in 2-capsule sub-tiles, b-quad/wave.
// R9 was latency-bound at 2 waves/EU (66 KB tile -> 2 blocks/CU); R10's
// register-prefetch spilled (WRITE 78 MB). This round: R9's proven
// stage-then-compute body, but sub-tile = 2 capsules (33 KB + 4 KB xbuf
// = ~38 KB LDS) and grid (256 i-blocks, 4 b-quarters) = 1024 blocks ->
// 4 blocks/CU = 4 waves/EU, double R9's occupancy at the same per-wave
// instruction stream. waves_per_eu(4,4) = 128-VGPR budget (R9 live set
// was 108).
// Lane = (c = lane&31, dg = lane>>5); wave owns b-quad by*16 + wave*4.
// MODE 0: uniform coupling 1/32. MODE 1: logits = dot(u, veff),
// veff transposed [b][dg][c][8].
template <int MODE>
__global__
__attribute__((amdgpu_flat_work_group_size(256, 256), amdgpu_waves_per_eu(4, 4)))
void route_pass(
    const float* __restrict__ x, const float* __restrict__ W,
    const float* __restrict__ veff, float* __restrict__ partial)
{
    // W sub-tile (2 capsules): float4 [(il*16 + k10)*2 + kdg][c 32 +1 pad]
    // stride 33 -> in-loop c-contiguous reads, 2-way max bank aliasing.
    __shared__ float4 wbuf[2112];   // 33 KB
    __shared__ float4 xbuf[512];    // [brel 16][cap*2+half], up to 8 KB

    const int ncap = NI / gridDim.x;              // 8 (16 if ws fallback)
    const int lg   = __builtin_ctz(ncap) + 1;     // log2(ncap*2)
    const int tid  = threadIdx.x;
    const int wave = tid >> 6;
    const int lane = tid & 63;
    const int c    = lane & 31;
    const int dg   = lane >> 5;
    const int brel0 = wave * 4;
    const int b0g  = blockIdx.y * 16;
    const int b0   = b0g + brel0;
    const int i0   = blockIdx.x * ncap;

    f8 s0 = {}, s1 = {}, s2 = {}, s3 = {};
    f8 va = {}, vb = {}, vc = {}, vd = {};
    if (MODE == 1) {
        va = *reinterpret_cast<const f8*>(veff + (((size_t)(b0+0)*2 + dg)*32 + c)*8);
        vb = *reinterpret_cast<const f8*>(veff + (((size_t)(b0+1)*2 + dg)*32 + c)*8);
        vc = *reinterpret_cast<const f8*>(veff + (((size_t)(b0+2)*2 + dg)*32 + c)*8);
        vd = *reinterpret_cast<const f8*>(veff + (((size_t)(b0+3)*2 + dg)*32 + c)*8);
    }

    const float4* Wf4 = reinterpret_cast<const float4*>(W);
    const float4* Xf4 = reinterpret_cast<const float4*>(x);

    // ---- stage x tile once: 16 b x ncap i x 8 f
    for (int idx = tid; idx < (16 << lg); idx += 256) {
        const int brel = idx >> lg;
        const int rem  = idx & ((1 << lg) - 1);       // cap*2 + half
        xbuf[(brel << lg) + rem] =
            Xf4[((size_t)(b0g + brel) * NI + i0 + (rem >> 1)) * 2 + (rem & 1)];
    }

    const int kk  = tid & 31;          // f4 index within a (c,i) W row
    const int p0  = tid >> 5;          // 0..7
    const int k10 = kk & 15, kdg = kk >> 4;

    for (int st = 0; st < (ncap >> 1); ++st) {
        const int i0s = i0 + st * 2;
        __syncthreads();               // previous sub-tile's readers done
        // ---- stage 2-capsule W sub-tile (coalesced 512 B runs)
        for (int r = 0; r < 8; ++r) {
            const int p  = r * 8 + p0;     // 0..63 = (cc 32, il 2)
            const int cc = p >> 1;
            const int il = p & 1;
            wbuf[((il * 16 + k10) * 2 + kdg) * 33 + cc] =
                Wf4[((size_t)cc * NI + i0s + il) * 32 + kk];
        }
        __syncthreads();

#pragma unroll
        for (int il = 0; il < 2; ++il) {
            const int cap = st * 2 + il;
            const float4 xa0 = xbuf[((brel0+0) << lg) + cap*2], xa1 = xbuf[((brel0+0) << lg) + cap*2 + 1];
            const float4 xb0 = xbuf[((brel0+1) << lg) + cap*2], xb1 = xbuf[((brel0+1) << lg) + cap*2 + 1];
            const float4 xc0 = xbuf[((brel0+2) << lg) + cap*2], xc1 = xbuf[((brel0+2) << lg) + cap*2 + 1];
            const float4 xd0 = xbuf[((brel0+3) << lg) + cap*2], xd1 = xbuf[((brel0+3) << lg) + cap*2 + 1];

            f8 u0 = {}, u1 = {}, u2 = {}, u3 = {};
#pragma unroll
            for (int dd = 0; dd < 8; ++dd) {
                const float4 wl = wbuf[((il*16 + dd*2    )*2 + dg)*33 + c];
                const float4 wh = wbuf[((il*16 + dd*2 + 1)*2 + dg)*33 + c];
                u0[dd] = wl.x*xa0.x + wl.y*xa0.y + wl.z*xa0.z + wl.w*xa0.w
                       + wh.x*xa1.x + wh.y*xa1.y + wh.z*xa1.z + wh.w*xa1.w;
                u1[dd] = wl.x*xb0.x + wl.y*xb0.y + wl.z*xb0.z + wl.w*xb0.w
                       + wh.x*xb1.x + wh.y*xb1.y + wh.z*xb1.z + wh.w*xb1.w;
                u2[dd] = wl.x*xc0.x + wl.y*xc0.y + wl.z*xc0.z + wl.w*xc0.w
                       + wh.x*xc1.x + wh.y*xc1.y + wh.z*xc1.z + wh.w*xc1.w;
                u3[dd] = wl.x*xd0.x + wl.y*xd0.y + wl.z*xd0.z + wl.w*xd0.w
                       + wh.x*xd1.x + wh.y*xd1.y + wh.z*xd1.z + wh.w*xd1.w;
            }

            if (MODE == 0) {
                const float cu = 1.0f / 32.0f;
                s0 += u0 * cu; s1 += u1 * cu; s2 += u2 * cu; s3 += u3 * cu;
            } else {
                // Pair-softmax: lower 32-half reduces even b, upper odd b;
                // one xor-32 merge in, one xor-32 coef-swap out.
#pragma unroll
                for (int pr = 0; pr < 2; ++pr) {
                    const f8& ue = pr ? u2 : u0;
                    const f8& uo = pr ? u3 : u1;
                    const f8& ve = pr ? vc : va;
                    const f8& vo = pr ? vd : vb;
                    float pe = 0.0f, po = 0.0f;
#pragma unroll
                    for (int k = 0; k < 8; ++k) {
                        pe += ue[k] * ve[k];
                        po += uo[k] * vo[k];
                    }
                    const float send = (dg == 0) ? po : pe;
                    const float recv = __shfl_xor(send, 32);
                    float a = ((dg == 0) ? pe : po) + recv;
                    float m = a;
#pragma unroll
                    for (int off = 16; off >= 1; off >>= 1)
                        m = fmaxf(m, __shfl_xor(m, off));
                    const float e = __expf(a - m);
                    float t = e;
#pragma unroll
                    for (int off = 16; off >= 1; off >>= 1)
                        t += __shfl_xor(t, off);
                    const float mine  = e / t;
                    const float other = __shfl_xor(mine, 32);
                    const float ce = (dg == 0) ? mine : other;
                    const float co = (dg == 0) ? other : mine;
                    if (pr == 0) { s0 += u0 * ce; s1 += u1 * co; }
                    else         { s2 += u2 * ce; s3 += u3 * co; }
                }
            }
        }
    }

    // ---- flush the wave's four s-partials (plain coalesced 32 B stores)
    // partial floats: [pblk][brel 16][dg 2][c 32][8]
    {
        const int pblk = blockIdx.y * gridDim.x + blockIdx.x;
        float* gp = partial +
            (((size_t)pblk * 16 + brel0) * 128 + dg * 64 + c * 2) * 4;
        *reinterpret_cast<f8*>(gp)        = s0;
        *reinterpret_cast<f8*>(gp +  512) = s1;
        *reinterpret_cast<f8*>(gp + 1024) = s2;
        *reinterpret_cast<f8*>(gp + 1536) = s3;
    }
}

// Fused partial reduction + squash. Squash's norm is per-(b,c), so split
// c across blocks too: 256 blocks = (b 64) x (c-octet 4), 256 threads =
// (part 8) x (ci 8 x dq 4). Each thread sums nib/8 slabs; LDS tree; the
// first 32 threads squash + write.
// phase 1: veff  = NI * squash(s)   (transposed [b][dg][c][8])
// phase 2: veff += NI * squash(s)
// phase 3: out   = squash(s)        (canonical [b][c][d])
__global__ __launch_bounds__(256) void reduce_squash(
    const float* __restrict__ partial, float* __restrict__ veff,
    float* __restrict__ out, int phase, int nib)
{
    __shared__ float4 red[256];
    const int b     = blockIdx.x >> 2;
    const int oct   = blockIdx.x & 3;
    const int tid   = threadIdx.x;
    const int part  = tid >> 5;
    const int inner = tid & 31;
    const int ci    = inner >> 2;
    const int c     = oct * 8 + ci;
    const int dq    = inner & 3;             // d = dq*4 + j
    const int chunk = nib >> 3;

    const float* base = partial
        + ((size_t)(b >> 4) * nib + part * chunk) * 8192
        + (b & 15) * 512 + (dq >> 1) * 256 + c * 8 + (dq & 1) * 4;
    float4 acc = make_float4(0.f, 0.f, 0.f, 0.f);
#pragma unroll 8
    for (int ib = 0; ib < chunk; ++ib) {
        const float4 p = *reinterpret_cast<const float4*>(base + (size_t)ib * 8192);
        acc.x += p.x; acc.y += p.y; acc.z += p.z; acc.w += p.w;
    }
    red[tid] = acc;
    __syncthreads();
    if (part == 0) {
#pragma unroll
        for (int p = 1; p < 8; ++p) {
            const float4 r = red[inner + p * 32];
            acc.x += r.x; acc.y += r.y; acc.z += r.z; acc.w += r.w;
        }

        float sq = acc.x*acc.x + acc.y*acc.y + acc.z*acc.z + acc.w*acc.w;
        sq += __shfl_xor(sq, 1);
        sq += __shfl_xor(sq, 2);
        const float scale = sq / ((1.0f + sq) * sqrtf(sq + SQ_EPS));

        if (phase == 3) {
            float4* op = reinterpret_cast<float4*>(
                out + ((size_t)b * NC + c) * DC + dq * 4);
            *op = make_float4(scale*acc.x, scale*acc.y, scale*acc.z, scale*acc.w);
        } else {
            const float ns = scale * (float)NI;
            float4* vp = reinterpret_cast<float4*>(
                veff + (((size_t)b * 2 + (dq >> 1)) * 32 + c) * 8 + (dq & 1) * 4);
            if (phase == 1) {
                *vp = make_float4(ns*acc.x, ns*acc.y, ns*acc.z, ns*acc.w);
            } else {
                float4 old = *vp;
                *vp = make_float4(old.x + ns*acc.x, old.y + ns*acc.y,
                                  old.z + ns*acc.z, old.w + ns*acc.w);
            }
        }
    }
}

extern "C" void kernel_launch(void* const* d_in, const int* in_sizes, int n_in,
                              void* d_out, int out_size, void* d_ws, size_t ws_size,
                              hipStream_t stream) {
    (void)in_sizes; (void)n_in; (void)out_size;
    const float* x = (const float*)d_in[0];
    const float* W = (const float*)d_in[1];

    float* partial = (float*)d_ws;
    float* veff    = (float*)d_out;     // scratch; phase-3 squash overwrites

    // 256 i-blocks needs 4*256 slabs * 32 KB = 33.6 MB of ws; fall back to
    // 128 i-blocks (16 capsules each, 16.8 MB) if the workspace is smaller.
    const int nib = (ws_size >= (size_t)4 * 256 * 8192 * 4) ? 256 : 128;
    const dim3 grid(nib, 4);

    // ---- iteration 1: uniform coupling
    route_pass<0><<<grid, 256, 0, stream>>>(x, W, nullptr, partial);
    reduce_squash<<<256, 256, 0, stream>>>(partial, veff, nullptr, 1, nib);

    // ---- iteration 2: logits = NI * <u, v1>
    route_pass<1><<<grid, 256, 0, stream>>>(x, W, veff, partial);
    reduce_squash<<<256, 256, 0, stream>>>(partial, veff, nullptr, 2, nib);

    // ---- iteration 3: logits = NI * (<u, v1> + <u, v2>)
    route_pass<1><<<grid, 256, 0, stream>>>(x, W, veff, partial);
    reduce_squash<<<256, 256, 0, stream>>>(partial, nullptr, (float*)d_out, 3, nib);
}